// Round 7
// baseline (88.687 us; speedup 1.0000x reference)
//
#include <hip/hip_runtime.h>
#include <math.h>

#define D_DIM   1024
#define BS      80      // B * STEP
#define STEPS   5
#define ALPHA   0.01f
#define BN_EPS  1e-5f
#define L2_EPS  1e-12f

// ---------------------------------------------------------------------------
// kQG: fused q-computation + GEMV  y = q @ W^T + b.
// Grid: 320 blocks x 512 threads. Block owns (jslice, ngroup):
//   jslice = blk & 31  -> j in [jslice*32, jslice*32+32)
//   ng     = blk >> 5  -> n in [ng*8,  ng*8+8)
//
// Phase 1 (fully parallel, unlike the round-5 serial version): wave `wid`
// alone computes q row n = ng*8+wid into LDS.
//   q[n,i] = ALPHA * sum_{s<=t} c_s * key_s[i] * prod_{r=s+1..t}(1-ALPHA*key_r[i]^2)
//   t = n>>4, bb = n&15, key_s = x[bb*5+s], c_s = dot(key_s, x[n]).
// Keys are loaded per-step and DISCARDED in the dot pass (<=60 live VGPRs),
// then reloaded (L2-hot) for the recurrence; the asm memory clobber between
// the passes blocks load-CSE so the compiler cannot keep all 5 keys live
// (that exact liveness extension caused the 85 MB scratch spill in round 4).
// q-rows are 32x redundant across jslices — trivial L2-hot compute.
//
// Phase 2: proven wave-GEMV — wave holds 4 W rows (64 VGPRs, coalesced
// float4), streams the 8 LDS q rows, 64-lane butterfly, lane 0 stores y
// as float4. No atomics, no stats buffer (kB recomputes stats from y).
// ---------------------------------------------------------------------------
__global__ __launch_bounds__(512) void kQG(const float* __restrict__ x,
                                           const float* __restrict__ W,
                                           const float* __restrict__ bvec,
                                           float* __restrict__ y) {
    __shared__ float qs[8 * D_DIM];   // 32 KB

    const int tid    = threadIdx.x;   // 0..511
    const int lane   = tid & 63;
    const int wid    = tid >> 6;      // 0..7
    const int blk    = blockIdx.x;    // 0..319
    const int jslice = blk & 31;
    const int ng     = blk >> 5;      // 0..9
    const int n0     = ng * 8;

    // ---- Phase 1: this wave's q row -> LDS ----
    {
        const int n  = n0 + wid;
        const int t  = n >> 4;        // wave-uniform
        const int bb = n & 15;

        const float4* __restrict__ xq = (const float4*)(x + (size_t)n * D_DIM);
        const float4 v0 = xq[lane +   0], v1 = xq[lane +  64];
        const float4 v2 = xq[lane + 128], v3 = xq[lane + 192];

        float p[STEPS];
#pragma unroll
        for (int s = 0; s < STEPS; ++s) {
            const float4* __restrict__ xk =
                (const float4*)(x + (size_t)(bb * STEPS + s) * D_DIM);
            const float4 k0 = xk[lane +   0], k1 = xk[lane +  64];
            const float4 k2 = xk[lane + 128], k3 = xk[lane + 192];
            p[s] = k0.x * v0.x + k0.y * v0.y + k0.z * v0.z + k0.w * v0.w
                 + k1.x * v1.x + k1.y * v1.y + k1.z * v1.z + k1.w * v1.w
                 + k2.x * v2.x + k2.y * v2.y + k2.z * v2.z + k2.w * v2.w
                 + k3.x * v3.x + k3.y * v3.y + k3.z * v3.z + k3.w * v3.w;
        }
#pragma unroll
        for (int off = 32; off; off >>= 1) {
#pragma unroll
            for (int s = 0; s < STEPS; ++s) p[s] += __shfl_xor(p[s], off, 64);
        }

        asm volatile("" ::: "memory");   // block load-CSE into the reload pass

        float4 a0 = make_float4(0.f, 0.f, 0.f, 0.f);
        float4 a1 = a0, a2 = a0, a3 = a0;
#pragma unroll
        for (int s = 0; s < STEPS; ++s) {
            if (s <= t) {                // wave-uniform predicate
                const float4* __restrict__ xk =
                    (const float4*)(x + (size_t)(bb * STEPS + s) * D_DIM);
                const float4 k0 = xk[lane +   0], k1 = xk[lane +  64];
                const float4 k2 = xk[lane + 128], k3 = xk[lane + 192];
                const float cs = p[s];
                a0.x = a0.x * (1.f - ALPHA * k0.x * k0.x) + cs * k0.x;
                a0.y = a0.y * (1.f - ALPHA * k0.y * k0.y) + cs * k0.y;
                a0.z = a0.z * (1.f - ALPHA * k0.z * k0.z) + cs * k0.z;
                a0.w = a0.w * (1.f - ALPHA * k0.w * k0.w) + cs * k0.w;
                a1.x = a1.x * (1.f - ALPHA * k1.x * k1.x) + cs * k1.x;
                a1.y = a1.y * (1.f - ALPHA * k1.y * k1.y) + cs * k1.y;
                a1.z = a1.z * (1.f - ALPHA * k1.z * k1.z) + cs * k1.z;
                a1.w = a1.w * (1.f - ALPHA * k1.w * k1.w) + cs * k1.w;
                a2.x = a2.x * (1.f - ALPHA * k2.x * k2.x) + cs * k2.x;
                a2.y = a2.y * (1.f - ALPHA * k2.y * k2.y) + cs * k2.y;
                a2.z = a2.z * (1.f - ALPHA * k2.z * k2.z) + cs * k2.z;
                a2.w = a2.w * (1.f - ALPHA * k2.w * k2.w) + cs * k2.w;
                a3.x = a3.x * (1.f - ALPHA * k3.x * k3.x) + cs * k3.x;
                a3.y = a3.y * (1.f - ALPHA * k3.y * k3.y) + cs * k3.y;
                a3.z = a3.z * (1.f - ALPHA * k3.z * k3.z) + cs * k3.z;
                a3.w = a3.w * (1.f - ALPHA * k3.w * k3.w) + cs * k3.w;
            }
        }
        float4* qrow = (float4*)qs;
        a0.x *= ALPHA; a0.y *= ALPHA; a0.z *= ALPHA; a0.w *= ALPHA;
        a1.x *= ALPHA; a1.y *= ALPHA; a1.z *= ALPHA; a1.w *= ALPHA;
        a2.x *= ALPHA; a2.y *= ALPHA; a2.z *= ALPHA; a2.w *= ALPHA;
        a3.x *= ALPHA; a3.y *= ALPHA; a3.z *= ALPHA; a3.w *= ALPHA;
        qrow[wid * 256 + lane +   0] = a0;
        qrow[wid * 256 + lane +  64] = a1;
        qrow[wid * 256 + lane + 128] = a2;
        qrow[wid * 256 + lane + 192] = a3;
    }
    __syncthreads();

    // ---- Phase 2: GEMV for this block's 32 columns x 8 rows ----
    const int j0 = jslice * 32 + wid * 4;

    const float4* __restrict__ W4 = (const float4*)W;
    float4 w[4][4];
#pragma unroll
    for (int jj = 0; jj < 4; ++jj)
#pragma unroll
        for (int m = 0; m < 4; ++m)
            w[jj][m] = W4[(size_t)(j0 + jj) * 256 + lane + 64 * m];

    const float4 b4 = ((const float4*)bvec)[j0 >> 2];
    const float4* qs4 = (const float4*)qs;

    for (int nn = 0; nn < 8; ++nn) {
        float4 qv[4];
#pragma unroll
        for (int m = 0; m < 4; ++m) qv[m] = qs4[nn * 256 + lane + 64 * m];

        float s[4] = {0.f, 0.f, 0.f, 0.f};
#pragma unroll
        for (int jj = 0; jj < 4; ++jj) {
#pragma unroll
            for (int m = 0; m < 4; ++m) {
                s[jj] += w[jj][m].x * qv[m].x + w[jj][m].y * qv[m].y
                       + w[jj][m].z * qv[m].z + w[jj][m].w * qv[m].w;
            }
        }
#pragma unroll
        for (int off = 32; off; off >>= 1) {
#pragma unroll
            for (int jj = 0; jj < 4; ++jj) s[jj] += __shfl_xor(s[jj], off, 64);
        }
        if (lane == 0) {
            ((float4*)y)[(size_t)(n0 + nn) * 256 + (j0 >> 2)] =
                make_float4(s[0] + b4.x, s[1] + b4.y, s[2] + b4.z, s[3] + b4.w);
        }
    }
}

// ---------------------------------------------------------------------------
// kB: BN (column stats over the 80-row batch, recomputed redundantly per
// block from y — 320 KB L2-hot stream) + ReLU + row L2-normalize.
// Grid: 80 blocks x 256 threads; thread owns one float4 column group.
// ---------------------------------------------------------------------------
__global__ __launch_bounds__(256) void kB(const float* __restrict__ y,
                                          const float* __restrict__ gamma,
                                          const float* __restrict__ beta,
                                          float* __restrict__ out) {
    const int n   = blockIdx.x;
    const int tid = threadIdx.x;

    const float4* __restrict__ y4 = (const float4*)y;

    float4 sum  = make_float4(0.f, 0.f, 0.f, 0.f);
    float4 sq   = make_float4(0.f, 0.f, 0.f, 0.f);
    float4 mine = make_float4(0.f, 0.f, 0.f, 0.f);
#pragma unroll 8
    for (int r = 0; r < BS; ++r) {
        const float4 v = y4[(size_t)r * 256 + tid];
        if (r == n) mine = v;
        sum.x += v.x; sum.y += v.y; sum.z += v.z; sum.w += v.w;
        sq.x += v.x * v.x; sq.y += v.y * v.y;
        sq.z += v.z * v.z; sq.w += v.w * v.w;
    }

    const float inv_bs = 1.f / (float)BS;
    const float4 g4  = ((const float4*)gamma)[tid];
    const float4 be4 = ((const float4*)beta)[tid];

    float4 o;
    {
        const float mux = sum.x * inv_bs, muy = sum.y * inv_bs;
        const float muz = sum.z * inv_bs, muw = sum.w * inv_bs;
        const float ix = rsqrtf(sq.x * inv_bs - mux * mux + BN_EPS);
        const float iy = rsqrtf(sq.y * inv_bs - muy * muy + BN_EPS);
        const float iz = rsqrtf(sq.z * inv_bs - muz * muz + BN_EPS);
        const float iw = rsqrtf(sq.w * inv_bs - muw * muw + BN_EPS);
        o.x = fmaxf((mine.x - mux) * ix * g4.x + be4.x, 0.f);
        o.y = fmaxf((mine.y - muy) * iy * g4.y + be4.y, 0.f);
        o.z = fmaxf((mine.z - muz) * iz * g4.z + be4.z, 0.f);
        o.w = fmaxf((mine.w - muw) * iw * g4.w + be4.w, 0.f);
    }

    float ss = o.x * o.x + o.y * o.y + o.z * o.z + o.w * o.w;
#pragma unroll
    for (int off = 32; off; off >>= 1) ss += __shfl_xor(ss, off, 64);
    __shared__ float sred[4];
    if ((tid & 63) == 0) sred[tid >> 6] = ss;
    __syncthreads();
    const float stot = sred[0] + sred[1] + sred[2] + sred[3];

    const float scale = 1.f / fmaxf(sqrtf(stot), L2_EPS);
    o.x *= scale; o.y *= scale; o.z *= scale; o.w *= scale;
    ((float4*)out)[(size_t)n * 256 + tid] = o;
}

extern "C" void kernel_launch(void* const* d_in, const int* in_sizes, int n_in,
                              void* d_out, int out_size, void* d_ws, size_t ws_size,
                              hipStream_t stream) {
    const float* x     = (const float*)d_in[0];
    const float* W     = (const float*)d_in[1];
    const float* bvec  = (const float*)d_in[2];
    const float* gamma = (const float*)d_in[3];
    const float* beta  = (const float*)d_in[4];

    float* y   = (float*)d_ws;        // 80*1024 floats
    float* out = (float*)d_out;

    kQG<<<320, 512, 0, stream>>>(x, W, bvec, y);
    kB <<<BS,  256, 0, stream>>>(y, gamma, beta, out);
}